// Round 1
// baseline (83.500 us; speedup 1.0000x reference)
//
#include <hip/hip_runtime.h>

#define ALPHA 1.0e-4f
#define NMAT 16
#define V 256
#define F 64
#define JT 16                      // columns (j) per block
#define S_ELEMS (NMAT * V * V)     // 1048576

__global__ __launch_bounds__(64) void zero_kernel(float* out) {
    if (threadIdx.x < 2) out[S_ELEMS + threadIdx.x] = 0.0f;
}

__global__ __launch_bounds__(256) void graph_learn_kernel(
        const float* __restrict__ x, const float* __restrict__ a,
        float* __restrict__ out) {
    const int n  = blockIdx.x >> 4;   // 0..15
    const int jt = blockIdx.x & 15;   // 0..15  (column tile)
    // xm = x[n, T//2=4, :, :]  -> offset (n*8 + 4) * 256*64
    const float* xm = x + (size_t)(n * 8 + 4) * (V * F);

    __shared__ float xj[JT][F];       // 4 KB: the 16 column vectors
    __shared__ float a_s[F];
    __shared__ float red[V][17];      // 17 KB: padded transpose for colsum
    __shared__ float part[16][17];
    __shared__ float colsum_s[JT];
    __shared__ float wred[8];

    const int t = threadIdx.x;        // row index i

    // stage 16 column vectors (1024 contiguous floats) + a into LDS
    ((float4*)xj)[t] = ((const float4*)(xm + jt * JT * F))[t];
    if (t < F) a_s[t] = a[t];
    __syncthreads();

    // this thread's row x_i into registers (64 floats, 16x dwordx4)
    float xi[F];
    {
        const float4* p = (const float4*)(xm + t * F);
        #pragma unroll
        for (int q = 0; q < F / 4; ++q) {
            float4 v = p[q];
            xi[4*q+0] = v.x; xi[4*q+1] = v.y; xi[4*q+2] = v.z; xi[4*q+3] = v.w;
        }
    }

    // fused: L1 scores (for S) and L2 distances (for dloss)
    float tmpS[JT];
    float d2sum = 0.0f;
    #pragma unroll
    for (int jj = 0; jj < JT; ++jj) {
        float sc = 0.0f, d2 = 0.0f;
        #pragma unroll
        for (int f = 0; f < F; ++f) {
            float d = xi[f] - xj[jj][f];
            sc = fmaf(fabsf(d), a_s[f], sc);
            d2 = fmaf(d, d, d2);
        }
        tmpS[jj] = __expf(fmaxf(sc, 0.0f));  // relu is a no-op (sc>=0) but kept
        d2sum += d2;
    }

    // ---- column sums over i (the 256 threads), per j ----
    #pragma unroll
    for (int jj = 0; jj < JT; ++jj) red[t][jj] = tmpS[jj];
    __syncthreads();
    {
        const int j = t & 15, c = t >> 4;
        float p = 0.0f;
        #pragma unroll
        for (int k = 0; k < 16; ++k) p += red[c * 16 + k][j];
        part[c][j] = p;
    }
    __syncthreads();
    if (t < JT) {
        float s = 0.0f;
        #pragma unroll
        for (int c = 0; c < 16; ++c) s += part[c][t];
        colsum_s[t] = s;
    }
    __syncthreads();

    // ---- normalize, write S, accumulate Sloss partial ----
    float slossp = 0.0f;
    float4 ov[JT / 4];
    #pragma unroll
    for (int jj = 0; jj < JT; ++jj) {
        float s = tmpS[jj] / colsum_s[jj];
        ((float*)ov)[jj] = s;
        slossp = fmaf(s, s, slossp);
    }
    {
        float4* dst = (float4*)(out + (size_t)n * (V * V) + (size_t)t * V + jt * JT);
        #pragma unroll
        for (int q = 0; q < JT / 4; ++q) dst[q] = ov[q];
    }

    // ---- scalar reductions: Sloss, dloss ----
    #pragma unroll
    for (int off = 32; off > 0; off >>= 1) {
        slossp += __shfl_down(slossp, off, 64);
        d2sum  += __shfl_down(d2sum,  off, 64);
    }
    const int wave = t >> 6, lane = t & 63;
    if (lane == 0) { wred[wave] = slossp; wred[4 + wave] = d2sum; }
    __syncthreads();
    if (t == 0) {
        float sl = wred[0] + wred[1] + wred[2] + wred[3];
        float dl = wred[4] + wred[5] + wred[6] + wred[7];
        atomicAdd(out + S_ELEMS,     (ALPHA / 16.0f) * sl);  // mean over N=16
        atomicAdd(out + S_ELEMS + 1, ALPHA * dl);
    }
}

extern "C" void kernel_launch(void* const* d_in, const int* in_sizes, int n_in,
                              void* d_out, int out_size, void* d_ws, size_t ws_size,
                              hipStream_t stream) {
    const float* x = (const float*)d_in[0];
    const float* a = (const float*)d_in[1];
    float* out = (float*)d_out;
    zero_kernel<<<1, 64, 0, stream>>>(out);
    graph_learn_kernel<<<NMAT * 16, 256, 0, stream>>>(x, a, out);
}

// Round 2
// 81.831 us; speedup vs baseline: 1.0204x; 1.0204x over previous
//
#include <hip/hip_runtime.h>

#define ALPHA 1.0e-4f
#define NMAT 16
#define V 256
#define F 64
#define JT 8                       // columns (j) per block
#define NJT (V / JT)               // 32 column tiles per n
#define S_ELEMS (NMAT * V * V)     // 1048576

__global__ __launch_bounds__(256) void graph_learn_kernel(
        const float* __restrict__ x, const float* __restrict__ a,
        float* __restrict__ out) {
    const int n  = blockIdx.x >> 5;         // 0..15
    const int jt = blockIdx.x & (NJT - 1);  // 0..31  (column tile)
    // xm = x[n, T//2=4, :, :]  -> offset (n*8 + 4) * 256*64
    const float* xm = x + (size_t)(n * 8 + 4) * (V * F);

    __shared__ float xj[JT][F];        // 2 KB: the 8 column vectors
    __shared__ float a_s[F];
    __shared__ float red[V][JT + 1];   // 9.2 KB: exp(scores), padded stride 9
    __shared__ float part[32][JT + 1];
    __shared__ float colsum_s[JT];
    __shared__ float wred[8];

    const int t = threadIdx.x;         // row index i

    // stage 8 column vectors (512 contiguous floats) + a into LDS
    if (t < (JT * F / 4)) ((float4*)xj)[t] = ((const float4*)(xm + jt * JT * F))[t];
    if (t < F) a_s[t] = a[t];
    __syncthreads();

    // this thread's row x_i into registers (fully static indexing -> VGPRs)
    float xi[F];
    {
        const float4* p = (const float4*)(xm + t * F);
        #pragma unroll
        for (int q = 0; q < F / 4; ++q) {
            float4 v = p[q];
            xi[4*q+0] = v.x; xi[4*q+1] = v.y; xi[4*q+2] = v.z; xi[4*q+3] = v.w;
        }
    }

    // fused: L1 scores (for S) and L2 distances (for dloss).
    // jj-loop is dynamic (scalar accumulators only -> no register arrays);
    // f-loop fully unrolled (xi[f] static -> registers).
    float d2sum = 0.0f;
    for (int jj = 0; jj < JT; ++jj) {
        float sc = 0.0f, d2 = 0.0f;
        #pragma unroll
        for (int f = 0; f < F; ++f) {
            float d = xi[f] - xj[jj][f];
            sc = fmaf(fabsf(d), a_s[f], sc);
            d2 = fmaf(d, d, d2);
        }
        d2sum += d2;
        red[t][jj] = __expf(sc);   // scores >= 0, relu is a no-op
    }
    __syncthreads();

    // ---- column sums over i (256 rows), per j ----
    {
        const int j = t & (JT - 1), c = t >> 3;   // 32 groups of 8 rows
        float p = 0.0f;
        #pragma unroll
        for (int k = 0; k < 8; ++k) p += red[c * 8 + k][j];
        part[c][j] = p;
    }
    __syncthreads();
    if (t < JT) {
        float s = 0.0f;
        #pragma unroll
        for (int c = 0; c < 32; ++c) s += part[c][t];
        colsum_s[t] = s;
    }
    __syncthreads();

    // ---- normalize, write S, accumulate Sloss partial ----
    float slossp = 0.0f;
    float4 ov[JT / 4];
    #pragma unroll
    for (int jj = 0; jj < JT; ++jj) {
        float s = red[t][jj] / colsum_s[jj];
        ((float*)ov)[jj] = s;
        slossp = fmaf(s, s, slossp);
    }
    {
        float4* dst = (float4*)(out + (size_t)n * (V * V) + (size_t)t * V + jt * JT);
        #pragma unroll
        for (int q = 0; q < JT / 4; ++q) dst[q] = ov[q];
    }

    // ---- scalar reductions: Sloss, dloss ----
    #pragma unroll
    for (int off = 32; off > 0; off >>= 1) {
        slossp += __shfl_down(slossp, off, 64);
        d2sum  += __shfl_down(d2sum,  off, 64);
    }
    const int wave = t >> 6, lane = t & 63;
    if (lane == 0) { wred[wave] = slossp; wred[4 + wave] = d2sum; }
    __syncthreads();
    if (t == 0) {
        float sl = wred[0] + wred[1] + wred[2] + wred[3];
        float dl = wred[4] + wred[5] + wred[6] + wred[7];
        atomicAdd(out + S_ELEMS,     (ALPHA / 16.0f) * sl);  // mean over N=16
        atomicAdd(out + S_ELEMS + 1, ALPHA * dl);
    }
}

extern "C" void kernel_launch(void* const* d_in, const int* in_sizes, int n_in,
                              void* d_out, int out_size, void* d_ws, size_t ws_size,
                              hipStream_t stream) {
    const float* x = (const float*)d_in[0];
    const float* a = (const float*)d_in[1];
    float* out = (float*)d_out;
    // zero the two scalar-loss slots (atomicAdd targets); memset node is
    // graph-capture legal and cheaper than a kernel launch
    hipMemsetAsync(out + S_ELEMS, 0, 2 * sizeof(float), stream);
    graph_learn_kernel<<<NMAT * NJT, 256, 0, stream>>>(x, a, out);
}